// Round 1
// baseline (250.672 us; speedup 1.0000x reference)
//
#include <hip/hip_runtime.h>

// WindowAttention fused kernel for MI355X (gfx950).
// Shapes fixed by the problem: D=256, H=8, hd=32, W=2048, T=64, N=98304.
#define DD   256
#define HH   8
#define HDIM 32
#define TT   64
#define WW   2048

typedef unsigned short u16;
typedef __attribute__((ext_vector_type(8))) __bf16 bf8_t;   // MFMA A/B frag (4 VGPR)
typedef __attribute__((ext_vector_type(4))) float  f32x4;   // MFMA C/D frag

__device__ __forceinline__ u16 f2bf(float x) {
  union { float f; unsigned u; } c; c.f = x;
  unsigned r = c.u + 0x7FFFu + ((c.u >> 16) & 1u);   // RNE
  return (u16)(r >> 16);
}
__device__ __forceinline__ int pack2(float a, float b) {
  return (int)((unsigned)f2bf(a) | ((unsigned)f2bf(b) << 16));
}

__global__ void prep_weights(const float* __restrict__ inw, const float* __restrict__ outw,
                             u16* __restrict__ wq, u16* __restrict__ wo) {
  int i = blockIdx.x * blockDim.x + threadIdx.x;
  if (i < 768 * 256) wq[i] = f2bf(inw[i]);
  if (i < 256 * 256) wo[i] = f2bf(outw[i]);
}

__global__ void build_slots(const int* __restrict__ widx, const int* __restrict__ sidx,
                            int* __restrict__ wslots, int n) {
  int i = blockIdx.x * blockDim.x + threadIdx.x;
  if (i < n) wslots[widx[i] * TT + sidx[i]] = i;
}

// One block per window; 8 waves, wave h = head h.
// MFMA 16x16x32 bf16 layouts used throughout (HW-verified per guide):
//   A-frag: A[row=l&15][k=8*(l>>4)+j]   (16B contiguous from row-major)
//   B-frag: B[k=8*(l>>4)+j][col=l&15]   (16B contiguous from B^T row-major)
//   C/D   : C[row=4*(l>>4)+reg][col=l&15]
__global__ __launch_bounds__(512) void fused_attn(
    const float* __restrict__ feat, const float* __restrict__ pos,
    const u16* __restrict__ wqkv,  // [768][256] bf16 (q rows 0-255, k 256-511, v 512-767)
    const u16* __restrict__ wout,  // [256][256] bf16
    const float* __restrict__ inb, const float* __restrict__ outb,
    const int* __restrict__ wslots, float* __restrict__ out) {

  // LDS. Row strides 144B / 528B: 16B-aligned (b128 ok) and ≡4 banks mod 32 (2-way = free).
  __shared__ int tl[TT];            // slot -> voxel row (-1 invalid)
  __shared__ u16 xqk[TT][72];       // x=feat+pos K-chunk [64 tok][64 k]
  __shared__ u16 xvs[TT][72];       // x=feat    K-chunk
  __shared__ u16 qld[TT][264];      // q [tok][dim]; reused as aout after scores
  __shared__ u16 kld[TT][264];      // k [tok][dim]
  __shared__ u16 vtl[DD][72];       // v^T [dim][tok]

  const int t    = threadIdx.x;
  const int h    = t >> 6;          // head = wave
  const int lane = t & 63;
  const int g    = lane >> 4;
  const int l16  = lane & 15;
  const int w    = blockIdx.x;

  if (t < TT) tl[t] = wslots[w * TT + t];
  __syncthreads();

  const f32x4 zf = {0.f, 0.f, 0.f, 0.f};

  // ================= Phase B: QKV projection =================
  f32x4 qa[4][2], ka[4][2], va[2][4];
#pragma unroll
  for (int mt = 0; mt < 4; ++mt)
#pragma unroll
    for (int nt = 0; nt < 2; ++nt) { qa[mt][nt] = zf; ka[mt][nt] = zf; }
#pragma unroll
  for (int md = 0; md < 2; ++md)
#pragma unroll
    for (int nt = 0; nt < 4; ++nt) va[md][nt] = zf;

  const int stok = t >> 3;            // staging: token this thread loads
  const int sds  = (t & 7) << 3;      // 8-dim segment within chunk
  const int srow = tl[stok];

  for (int kc = 0; kc < 4; ++kc) {    // K-chunks of 64
    {
      union { u16 u[8]; bf8_t v; } aq, av_;
      if (srow >= 0) {
        const float4* fp = (const float4*)(feat + (size_t)srow * DD + kc * 64 + sds);
        const float4* pp = (const float4*)(pos  + (size_t)srow * DD + kc * 64 + sds);
        float4 f0 = fp[0], f1 = fp[1], p0 = pp[0], p1 = pp[1];
        float fr[8] = {f0.x, f0.y, f0.z, f0.w, f1.x, f1.y, f1.z, f1.w};
        float pr[8] = {p0.x, p0.y, p0.z, p0.w, p1.x, p1.y, p1.z, p1.w};
#pragma unroll
        for (int j = 0; j < 8; ++j) { aq.u[j] = f2bf(fr[j] + pr[j]); av_.u[j] = f2bf(fr[j]); }
      } else {
#pragma unroll
        for (int j = 0; j < 8; ++j) { aq.u[j] = 0; av_.u[j] = 0; }
      }
      *(bf8_t*)&xqk[stok][sds] = aq.v;
      *(bf8_t*)&xvs[stok][sds] = av_.v;
    }
    __syncthreads();

    bf8_t ax[4][2], bx[4][2];
#pragma unroll
    for (int mt = 0; mt < 4; ++mt)
#pragma unroll
      for (int ks = 0; ks < 2; ++ks) {
        ax[mt][ks] = *(const bf8_t*)&xqk[mt * 16 + l16][ks * 32 + g * 8];
        bx[mt][ks] = *(const bf8_t*)&xvs[mt * 16 + l16][ks * 32 + g * 8];
      }

#pragma unroll
    for (int ks = 0; ks < 2; ++ks) {
      const int kb = kc * 64 + ks * 32 + g * 8;   // global k offset of this frag
#pragma unroll
      for (int nt = 0; nt < 2; ++nt) {
        bf8_t bwq = *(const bf8_t*)(wqkv + (size_t)(h * 32 + nt * 16 + l16) * DD + kb);
#pragma unroll
        for (int mt = 0; mt < 4; ++mt)
          qa[mt][nt] = __builtin_amdgcn_mfma_f32_16x16x32_bf16(ax[mt][ks], bwq, qa[mt][nt], 0, 0, 0);
        bf8_t bwk = *(const bf8_t*)(wqkv + (size_t)(256 + h * 32 + nt * 16 + l16) * DD + kb);
#pragma unroll
        for (int mt = 0; mt < 4; ++mt)
          ka[mt][nt] = __builtin_amdgcn_mfma_f32_16x16x32_bf16(ax[mt][ks], bwk, ka[mt][nt], 0, 0, 0);
      }
#pragma unroll
      for (int md = 0; md < 2; ++md) {
        bf8_t awv = *(const bf8_t*)(wqkv + (size_t)(512 + h * 32 + md * 16 + l16) * DD + kb);
#pragma unroll
        for (int nt = 0; nt < 4; ++nt)
          va[md][nt] = __builtin_amdgcn_mfma_f32_16x16x32_bf16(awv, bx[nt][ks], va[md][nt], 0, 0, 0);
      }
    }
    __syncthreads();   // before restaging x chunk
  }

  // biases + write q,k (row=tok, col=dim) and v^T (row=dim, col=tok) to LDS (own head's cols/rows)
#pragma unroll
  for (int nt = 0; nt < 2; ++nt) {
    float bq = inb[h * 32 + nt * 16 + l16];
    float bk = inb[256 + h * 32 + nt * 16 + l16];
#pragma unroll
    for (int mt = 0; mt < 4; ++mt)
#pragma unroll
      for (int r = 0; r < 4; ++r) {
        qld[mt * 16 + 4 * g + r][h * 32 + nt * 16 + l16] = f2bf(qa[mt][nt][r] + bq);
        kld[mt * 16 + 4 * g + r][h * 32 + nt * 16 + l16] = f2bf(ka[mt][nt][r] + bk);
      }
  }
#pragma unroll
  for (int md = 0; md < 2; ++md)
#pragma unroll
    for (int r = 0; r < 4; ++r) {
      float bv = inb[512 + h * 32 + md * 16 + 4 * g + r];
#pragma unroll
      for (int nt = 0; nt < 4; ++nt)
        vtl[h * 32 + md * 16 + 4 * g + r][nt * 16 + l16] = f2bf(va[md][nt][r] + bv);
    }

  // ================= Phase C: attention (swapped QK^T -> S^T) =================
  // S^T[tok][q] = K·Q^T ; lane holds S^T[mt*16+4g+r][nt*16+l16]
  bf8_t akf[4], bqf[4];
#pragma unroll
  for (int mt = 0; mt < 4; ++mt) akf[mt] = *(const bf8_t*)&kld[mt * 16 + l16][h * 32 + g * 8];
#pragma unroll
  for (int nt = 0; nt < 4; ++nt) bqf[nt] = *(const bf8_t*)&qld[nt * 16 + l16][h * 32 + g * 8];

  f32x4 sa[4][4];
#pragma unroll
  for (int mt = 0; mt < 4; ++mt)
#pragma unroll
    for (int nt = 0; nt < 4; ++nt)
      sa[mt][nt] = __builtin_amdgcn_mfma_f32_16x16x32_bf16(akf[mt], bqf[nt], zf, 0, 0, 0);

  __syncthreads();   // all q-reads done -> qld reusable as aout

  // masked softmax along tok (rows of S^T). Row q is lane-local across 4 lane-groups.
  bool vm[4][4];
#pragma unroll
  for (int mt = 0; mt < 4; ++mt)
#pragma unroll
    for (int r = 0; r < 4; ++r) vm[mt][r] = (tl[mt * 16 + 4 * g + r] >= 0);

  const float scale = 0.17677669529663687f;  // 1/sqrt(32)
  int pk[4][4][2];                            // packed bf16 pairs of P^T, per [tok-tile][q-tile]
#pragma unroll
  for (int nt = 0; nt < 4; ++nt) {
    float sv[4][4];
    float m = -3e38f;
#pragma unroll
    for (int mt = 0; mt < 4; ++mt)
#pragma unroll
      for (int r = 0; r < 4; ++r) {
        float s = vm[mt][r] ? sa[mt][nt][r] * scale : -3e38f;
        sv[mt][r] = s;
        m = fmaxf(m, s);
      }
    m = fmaxf(m, __shfl_xor(m, 16, 64));
    m = fmaxf(m, __shfl_xor(m, 32, 64));
    float sum = 0.f;
#pragma unroll
    for (int mt = 0; mt < 4; ++mt)
#pragma unroll
      for (int r = 0; r < 4; ++r) {
        float p = vm[mt][r] ? __expf(sv[mt][r] - m) : 0.f;
        sv[mt][r] = p;
        sum += p;
      }
    sum += __shfl_xor(sum, 16, 64);
    sum += __shfl_xor(sum, 32, 64);
    float inv = sum > 0.f ? 1.f / sum : 0.f;
#pragma unroll
    for (int mt = 0; mt < 4; ++mt)
#pragma unroll
      for (int rp = 0; rp < 2; ++rp)
        pk[mt][nt][rp] = pack2(sv[mt][2 * rp] * inv, sv[mt][2 * rp + 1] * inv);
  }

  // PV: out^T = V^T · P^T. B-frags of P^T gathered by shuffle from score C-frags.
  bf8_t avf[2][2];
#pragma unroll
  for (int md = 0; md < 2; ++md)
#pragma unroll
    for (int kk = 0; kk < 2; ++kk)
      avf[md][kk] = *(const bf8_t*)&vtl[h * 32 + md * 16 + l16][kk * 32 + g * 8];

  f32x4 oa[2][4];
#pragma unroll
  for (int md = 0; md < 2; ++md)
#pragma unroll
    for (int nt = 0; nt < 4; ++nt) oa[md][nt] = zf;

#pragma unroll
  for (int kk = 0; kk < 2; ++kk) {
#pragma unroll
    for (int nt = 0; nt < 4; ++nt) {
      union { int wd[4]; bf8_t v; } bu;
#pragma unroll
      for (int wd = 0; wd < 4; ++wd) {
        int src = l16 + 16 * (2 * (g & 1) + (wd >> 1));
        int lo = __shfl(pk[2 * kk + 0][nt][wd & 1], src, 64);
        int hi = __shfl(pk[2 * kk + 1][nt][wd & 1], src, 64);
        bu.wd[wd] = (g & 2) ? hi : lo;
      }
#pragma unroll
      for (int md = 0; md < 2; ++md)
        oa[md][nt] = __builtin_amdgcn_mfma_f32_16x16x32_bf16(avf[md][kk], bu.v, oa[md][nt], 0, 0, 0);
    }
  }

  // aout[tok][dim] into reused qld
#pragma unroll
  for (int md = 0; md < 2; ++md)
#pragma unroll
    for (int nt = 0; nt < 4; ++nt)
#pragma unroll
      for (int r = 0; r < 4; ++r)
        qld[nt * 16 + l16][h * 32 + md * 16 + 4 * g + r] = f2bf(oa[md][nt][r]);
  __syncthreads();   // out_proj reads all dims (cross-wave)

  // ================= Phase D: out_proj =================
  f32x4 fa[4][2];
#pragma unroll
  for (int mt = 0; mt < 4; ++mt)
#pragma unroll
    for (int nt = 0; nt < 2; ++nt) fa[mt][nt] = zf;

#pragma unroll
  for (int kk = 0; kk < 8; ++kk) {
    bf8_t aa[4];
#pragma unroll
    for (int mt = 0; mt < 4; ++mt)
      aa[mt] = *(const bf8_t*)&qld[mt * 16 + l16][kk * 32 + g * 8];
#pragma unroll
    for (int nt = 0; nt < 2; ++nt) {
      bf8_t bw = *(const bf8_t*)(wout + (size_t)(h * 32 + nt * 16 + l16) * DD + kk * 32 + g * 8);
#pragma unroll
      for (int mt = 0; mt < 4; ++mt)
        fa[mt][nt] = __builtin_amdgcn_mfma_f32_16x16x32_bf16(aa[mt], bw, fa[mt][nt], 0, 0, 0);
    }
  }

#pragma unroll
  for (int nt = 0; nt < 2; ++nt) {
    float ob = outb[h * 32 + nt * 16 + l16];
#pragma unroll
    for (int mt = 0; mt < 4; ++mt)
#pragma unroll
      for (int r = 0; r < 4; ++r) {
        int tok = mt * 16 + 4 * g + r;
        int row = tl[tok];
        if (row >= 0)
          out[(size_t)row * DD + h * 32 + nt * 16 + l16] = fa[mt][nt][r] + ob;
      }
  }
}

extern "C" void kernel_launch(void* const* d_in, const int* in_sizes, int n_in,
                              void* d_out, int out_size, void* d_ws, size_t ws_size,
                              hipStream_t stream) {
  (void)n_in; (void)out_size; (void)ws_size;
  const float* feat = (const float*)d_in[0];
  const float* pos  = (const float*)d_in[1];
  const float* inw  = (const float*)d_in[2];
  const float* inb  = (const float*)d_in[3];
  const float* outw = (const float*)d_in[4];
  const float* outb = (const float*)d_in[5];
  const int*   widx = (const int*)d_in[6];
  const int*   sidx = (const int*)d_in[7];
  const int N = in_sizes[0] / DD;

  char* ws = (char*)d_ws;
  u16* wqkv   = (u16*)ws;                          // 768*256*2 = 393216 B
  u16* wout   = (u16*)(ws + 393216);               // 256*256*2 = 131072 B
  int* wslots = (int*)(ws + 393216 + 131072);      // 2048*64*4 = 524288 B

  hipMemsetAsync(wslots, 0xFF, WW * TT * sizeof(int), stream);
  prep_weights<<<768, 256, 0, stream>>>(inw, outw, wqkv, wout);
  build_slots<<<(N + 255) / 256, 256, 0, stream>>>(widx, sidx, wslots, N);
  fused_attn<<<WW, 512, 0, stream>>>(feat, pos, wqkv, wout, inb, outb, wslots, (float*)d_out);
}